// Round 1
// baseline (150.132 us; speedup 1.0000x reference)
//
#include <hip/hip_runtime.h>

// Problem constants (fixed by reference setup_inputs)
#define B_    64
#define K_    4
#define M_    3
#define NPIX  65536       // X*Y = 256*256
#define CHUNKS 64         // blocks per image
#define TPB   256         // threads per block
#define NV    16          // 4 den + 12 num partials per thread

// Each block handles NPIX/CHUNKS = 1024 pixels: 256 threads x one float4 each.
__global__ __launch_bounds__(TPB) void partial_kernel(
    const float* __restrict__ pred,    // [B,K,NPIX]
    const float* __restrict__ inp,     // [B,M,NPIX]
    const int*   __restrict__ heart,   // [B,NPIX]
    float* __restrict__ num_ws,        // [B,K,M]
    float* __restrict__ den_ws)        // [B,K]
{
    const int b     = blockIdx.x >> 6;   // /CHUNKS
    const int chunk = blockIdx.x & 63;
    const int pix   = chunk * (NPIX / CHUNKS) + (int)threadIdx.x * 4;

    const int4 h = *reinterpret_cast<const int4*>(heart + (size_t)b * NPIX + pix);
    float4 mask;
    mask.x = (h.x == 1) ? 1.0f : 0.0f;
    mask.y = (h.y == 1) ? 1.0f : 0.0f;
    mask.z = (h.z == 1) ? 1.0f : 0.0f;
    mask.w = (h.w == 1) ? 1.0f : 0.0f;

    float4 in[M_];
#pragma unroll
    for (int m = 0; m < M_; ++m)
        in[m] = *reinterpret_cast<const float4*>(inp + ((size_t)b * M_ + m) * NPIX + pix);

    // val[0..3] = den[k]; val[4 + k*3 + m] = num[k][m]
    float val[NV];
#pragma unroll
    for (int k = 0; k < K_; ++k) {
        float4 p = *reinterpret_cast<const float4*>(pred + ((size_t)b * K_ + k) * NPIX + pix);
        float4 pm;
        pm.x = p.x * mask.x; pm.y = p.y * mask.y;
        pm.z = p.z * mask.z; pm.w = p.w * mask.w;
        val[k] = (pm.x + pm.y) + (pm.z + pm.w);
#pragma unroll
        for (int m = 0; m < M_; ++m)
            val[4 + k * M_ + m] = pm.x * in[m].x + pm.y * in[m].y
                                + pm.z * in[m].z + pm.w * in[m].w;
    }

    // wave64 shuffle reduction (result lands on lane 0 of each wave)
#pragma unroll
    for (int off = 32; off > 0; off >>= 1) {
#pragma unroll
        for (int i = 0; i < NV; ++i)
            val[i] += __shfl_down(val[i], off, 64);
    }

    __shared__ float smem[TPB / 64][NV];
    const int lane = threadIdx.x & 63;
    const int wave = threadIdx.x >> 6;
    if (lane == 0) {
#pragma unroll
        for (int i = 0; i < NV; ++i) smem[wave][i] = val[i];
    }
    __syncthreads();

    if (threadIdx.x < NV) {
        float s = smem[0][threadIdx.x] + smem[1][threadIdx.x]
                + smem[2][threadIdx.x] + smem[3][threadIdx.x];
        if (threadIdx.x < K_)
            atomicAdd(&den_ws[b * K_ + threadIdx.x], s);
        else
            atomicAdd(&num_ws[b * (K_ * M_) + (threadIdx.x - K_)], s);
    }
}

// One wave: lane b owns batch element b; reduce the 12 ratios over b.
__global__ __launch_bounds__(64) void finalize_kernel(
    const float* __restrict__ num_ws,   // [B,K,M]
    const float* __restrict__ den_ws,   // [B,K]
    const float* __restrict__ mu_data,  // [K,M]
    float* __restrict__ out)            // [1]
{
    const int b = threadIdx.x;  // 0..63 == B_
    float r[K_ * M_];
#pragma unroll
    for (int k = 0; k < K_; ++k) {
        const float den = den_ws[b * K_ + k] + 1e-10f;
        const float inv = 1.0f / den;
#pragma unroll
        for (int m = 0; m < M_; ++m)
            r[k * M_ + m] = num_ws[b * (K_ * M_) + k * M_ + m] * inv;
    }
#pragma unroll
    for (int off = 32; off > 0; off >>= 1) {
#pragma unroll
        for (int i = 0; i < K_ * M_; ++i)
            r[i] += __shfl_down(r[i], off, 64);
    }
    if (b == 0) {
        float s = 0.0f;
#pragma unroll
        for (int i = 0; i < K_ * M_; ++i) {
            const float d = mu_data[i] - r[i] * (1.0f / (float)B_);
            s += d * d;
        }
        out[0] = s;
    }
}

extern "C" void kernel_launch(void* const* d_in, const int* in_sizes, int n_in,
                              void* d_out, int out_size, void* d_ws, size_t ws_size,
                              hipStream_t stream) {
    const float* pred    = (const float*)d_in[0];  // [64,4,256,256] f32
    const float* inp     = (const float*)d_in[1];  // [64,3,256,256] f32
    const int*   heart   = (const int*)d_in[2];    // [64,1,256,256] i32
    const float* mu_data = (const float*)d_in[3];  // [4,3] f32
    float* out = (float*)d_out;

    float* num_ws = (float*)d_ws;                  // [B,K,M]
    float* den_ws = num_ws + B_ * K_ * M_;         // [B,K]

    // d_ws is poisoned 0xAA before every timed call — zero the accumulators.
    hipMemsetAsync(d_ws, 0, (size_t)(B_ * K_ * M_ + B_ * K_) * sizeof(float), stream);

    partial_kernel<<<B_ * CHUNKS, TPB, 0, stream>>>(pred, inp, heart, num_ws, den_ws);
    finalize_kernel<<<1, 64, 0, stream>>>(num_ws, den_ws, mu_data, out);
}